// Round 3
// baseline (524.627 us; speedup 1.0000x reference)
//
#include <hip/hip_runtime.h>

// Problem constants (fixed by setup_inputs) — all tensors fp32 on the wire.
#define C_CH  512
#define R_CH  128
#define BATCH 8
#define HW    16384                 // 128*128
#define HW4   (HW / 4)              // 4096 float4 per plane
#define NPLANE (BATCH * C_CH)       // 4096

__device__ __forceinline__ float relu6f(float v) {
    return fminf(fmaxf(v, 0.0f), 6.0f);
}

// ---- Kernel 1: per-(b,c) plane mean. One block per plane, float4 loads. ----
__global__ __launch_bounds__(256) void mean_kernel(const float4* __restrict__ x,
                                                   float* __restrict__ meanv) {
    const int plane = blockIdx.x;
    const float4* px = x + (size_t)plane * HW4;
    float s = 0.0f;
#pragma unroll
    for (int it = 0; it < HW4 / 256; ++it) {
        float4 v = px[threadIdx.x + it * 256];
        s += (v.x + v.y) + (v.z + v.w);
    }
    __shared__ float red[256];
    red[threadIdx.x] = s;
    __syncthreads();
    for (int off = 128; off > 0; off >>= 1) {
        if (threadIdx.x < off) red[threadIdx.x] += red[threadIdx.x + off];
        __syncthreads();
    }
    if (threadIdx.x == 0) meanv[plane] = red[0] * (1.0f / (float)HW);
}

// ---- Kernel 2: relu6(Wg @ m) -> relu6(BN(Wf @ t)). One block per batch. ----
__global__ __launch_bounds__(256) void mlp_kernel(
    const float* __restrict__ meanv,
    const float* __restrict__ wg,      // [R_CH, C_CH]
    const float* __restrict__ wf,      // [C_CH, R_CH]
    const float* __restrict__ gamma,
    const float* __restrict__ beta,
    const float* __restrict__ mu,
    const float* __restrict__ var,
    float* __restrict__ yv) {
    const int b = blockIdx.x;
    __shared__ float m[C_CH];
    __shared__ float t[R_CH];
    for (int c = threadIdx.x; c < C_CH; c += 256) m[c] = meanv[b * C_CH + c];
    __syncthreads();
    if (threadIdx.x < R_CH) {
        const int r = threadIdx.x;
        const float4* w4 = (const float4*)(wg + (size_t)r * C_CH);
        float a0 = 0.f, a1 = 0.f;
#pragma unroll 8
        for (int i = 0; i < C_CH / 4; ++i) {
            float4 v = w4[i];
            const int c = i * 4;
            a0 += v.x * m[c + 0] + v.y * m[c + 1];
            a1 += v.z * m[c + 2] + v.w * m[c + 3];
        }
        t[r] = relu6f(a0 + a1);
    }
    __syncthreads();
    for (int c = threadIdx.x; c < C_CH; c += 256) {
        const float4* w4 = (const float4*)(wf + (size_t)c * R_CH);
        float a0 = 0.f, a1 = 0.f;
#pragma unroll
        for (int i = 0; i < R_CH / 4; ++i) {
            float4 v = w4[i];
            const int r = i * 4;
            a0 += v.x * t[r + 0] + v.y * t[r + 1];
            a1 += v.z * t[r + 2] + v.w * t[r + 3];
        }
        const float s = a0 + a1;
        const float inv_std = 1.0f / sqrtf(var[c] + 1e-5f);
        const float v2 = (s - mu[c]) * inv_std * gamma[c] + beta[c];
        yv[b * C_CH + c] = relu6f(v2);
    }
}

// ---- Kernel 3: out = x + y[plane]. One block per plane, float4. ----
__global__ __launch_bounds__(256) void add_kernel(const float4* __restrict__ x,
                                                  const float* __restrict__ yv,
                                                  float4* __restrict__ out) {
    const int plane = blockIdx.x;
    const float a = yv[plane];
    const float4* px = x + (size_t)plane * HW4;
    float4* po = out + (size_t)plane * HW4;
#pragma unroll
    for (int it = 0; it < HW4 / 256; ++it) {
        const int i = threadIdx.x + it * 256;
        float4 v = px[i];
        v.x += a; v.y += a; v.z += a; v.w += a;
        po[i] = v;
    }
}

extern "C" void kernel_launch(void* const* d_in, const int* in_sizes, int n_in,
                              void* d_out, int out_size, void* d_ws, size_t ws_size,
                              hipStream_t stream) {
    const float4* x4  = (const float4*)d_in[0];
    const float* wg   = (const float*)d_in[1];
    const float* wf   = (const float*)d_in[2];
    const float* gamma = (const float*)d_in[3];
    const float* beta  = (const float*)d_in[4];
    const float* mu    = (const float*)d_in[5];
    const float* var   = (const float*)d_in[6];

    float* meanv = (float*)d_ws;        // NPLANE floats
    float* yv    = meanv + NPLANE;      // NPLANE floats
    float4* out  = (float4*)d_out;

    mean_kernel<<<NPLANE, 256, 0, stream>>>(x4, meanv);
    mlp_kernel<<<BATCH, 256, 0, stream>>>(meanv, wg, wf, gamma, beta, mu, var, yv);
    add_kernel<<<NPLANE, 256, 0, stream>>>(x4, yv, out);
}